// Round 1
// baseline (108.343 us; speedup 1.0000x reference)
//
#include <hip/hip_runtime.h>

#define KN   4096
#define LTOT 6
#define BATCH 8192
#define NTHREADS 256

// f_i(a,b) = c1 + ca*a + cb*b + cab*a*b
__global__ __launch_bounds__(NTHREADS) void coeff_kernel(const float* __restrict__ w0,
                                                         const float* __restrict__ ws,
                                                         float4* __restrict__ cs) {
    const float TAB[16][4] = {
        {0.f, 0.f, 0.f, 0.f}, {0.f, 0.f, 0.f, 1.f}, {0.f, 1.f, 0.f,-1.f}, {0.f, 1.f, 0.f, 0.f},
        {0.f, 0.f, 1.f,-1.f}, {0.f, 0.f, 1.f, 0.f}, {0.f, 1.f, 1.f,-2.f}, {0.f, 1.f, 1.f,-1.f},
        {1.f,-1.f,-1.f, 1.f}, {1.f,-1.f,-1.f, 2.f}, {1.f, 0.f,-1.f, 0.f}, {1.f, 0.f,-1.f, 1.f},
        {1.f,-1.f, 0.f, 0.f}, {1.f,-1.f, 0.f, 1.f}, {1.f, 0.f, 0.f,-1.f}, {1.f, 0.f, 0.f, 0.f}
    };
    int gid = blockIdx.x * NTHREADS + threadIdx.x;
    if (gid >= LTOT * KN) return;
    int l = gid >> 12;             // gid / KN
    int k = gid & (KN - 1);
    const float* w = (l == 0) ? (w0 + k * 16) : (ws + ((size_t)((l - 1) * KN + k) << 4));
    float wv[16];
    float m = -1e30f;
#pragma unroll
    for (int j = 0; j < 16; ++j) { wv[j] = w[j]; m = fmaxf(m, wv[j]); }
    float s = 0.f;
#pragma unroll
    for (int j = 0; j < 16; ++j) { wv[j] = __expf(wv[j] - m); s += wv[j]; }
    float inv = 1.0f / s;
    float c0 = 0.f, c1 = 0.f, c2 = 0.f, c3 = 0.f;
#pragma unroll
    for (int j = 0; j < 16; ++j) {
        c0 += wv[j] * TAB[j][0];
        c1 += wv[j] * TAB[j][1];
        c2 += wv[j] * TAB[j][2];
        c3 += wv[j] * TAB[j][3];
    }
    cs[gid] = make_float4(c0 * inv, c1 * inv, c2 * inv, c3 * inv);
}

// One block = 2 batch rows, packed per-neuron as float2 in LDS.
__global__ __launch_bounds__(NTHREADS) void fused_kernel(const float* __restrict__ x,
                                                         const int* __restrict__ idx0,
                                                         const int* __restrict__ idxs,
                                                         const float4* __restrict__ cs,
                                                         float* __restrict__ out) {
    __shared__ float2 hbuf[2][KN];          // 64 KB
    __shared__ float red[4][4];

    const int t  = threadIdx.x;
    const int b0 = blockIdx.x * 2;

    // Binarize the two input rows (2 features each).
    float2 hin0, hin1;  // feature 0 / feature 1, .x = row b0, .y = row b0+1
    hin0.x = (x[(b0 + 0) * 2 + 0] > 0.f) ? 1.f : 0.f;
    hin0.y = (x[(b0 + 1) * 2 + 0] > 0.f) ? 1.f : 0.f;
    hin1.x = (x[(b0 + 0) * 2 + 1] > 0.f) ? 1.f : 0.f;
    hin1.y = (x[(b0 + 1) * 2 + 1] > 0.f) ? 1.f : 0.f;

    // Layer 0: 2 -> K
#pragma unroll 4
    for (int k = t; k < KN; k += NTHREADS) {
        int ia = idx0[k];
        int ib = idx0[KN + k];
        float4 c = cs[k];
        float2 a = ia ? hin1 : hin0;
        float2 b = ib ? hin1 : hin0;
        float2 o;
        o.x = fmaf(fmaf(c.w, b.x, c.y), a.x, fmaf(c.z, b.x, c.x));
        o.y = fmaf(fmaf(c.w, b.y, c.y), a.y, fmaf(c.z, b.y, c.x));
        hbuf[0][k] = o;
    }
    __syncthreads();

    // Layers 1..5: K -> K, ping-pong LDS buffers.
    int cur = 0;
    for (int l = 1; l < LTOT; ++l) {
        const int*    ixa = idxs + (size_t)(l - 1) * 2 * KN;
        const int*    ixb = ixa + KN;
        const float4* cl  = cs + (size_t)l * KN;
        const float2* hs  = hbuf[cur];
        float2*       hd  = hbuf[cur ^ 1];
#pragma unroll 4
        for (int k = t; k < KN; k += NTHREADS) {
            int ia = ixa[k];
            int ib = ixb[k];
            float4 c = cl[k];
            float2 a = hs[ia];
            float2 b = hs[ib];
            float2 o;
            o.x = fmaf(fmaf(c.w, b.x, c.y), a.x, fmaf(c.z, b.x, c.x));
            o.y = fmaf(fmaf(c.w, b.y, c.y), a.y, fmaf(c.z, b.y, c.x));
            hd[k] = o;
        }
        __syncthreads();
        cur ^= 1;
    }

    // GroupSum: class 0 = k in [0,2048), class 1 = k in [2048,4096)
    const float2* hf = hbuf[cur];
    float2 s0 = make_float2(0.f, 0.f), s1 = make_float2(0.f, 0.f);
    for (int k = t; k < KN / 2; k += NTHREADS) {
        float2 v = hf[k];
        s0.x += v.x; s0.y += v.y;
    }
    for (int k = KN / 2 + t; k < KN; k += NTHREADS) {
        float2 v = hf[k];
        s1.x += v.x; s1.y += v.y;
    }
#pragma unroll
    for (int off = 32; off > 0; off >>= 1) {
        s0.x += __shfl_down(s0.x, off);
        s0.y += __shfl_down(s0.y, off);
        s1.x += __shfl_down(s1.x, off);
        s1.y += __shfl_down(s1.y, off);
    }
    int wave = t >> 6, lane = t & 63;
    if (lane == 0) {
        red[wave][0] = s0.x; red[wave][1] = s0.y;
        red[wave][2] = s1.x; red[wave][3] = s1.y;
    }
    __syncthreads();
    if (t == 0) {
        float r00 = red[0][0] + red[1][0] + red[2][0] + red[3][0]; // row b0,   class 0
        float r01 = red[0][1] + red[1][1] + red[2][1] + red[3][1]; // row b0+1, class 0
        float r10 = red[0][2] + red[1][2] + red[2][2] + red[3][2]; // row b0,   class 1
        float r11 = red[0][3] + red[1][3] + red[2][3] + red[3][3]; // row b0+1, class 1
        out[(b0 + 0) * 2 + 0] = r00;
        out[(b0 + 1) * 2 + 0] = r01;
        out[(b0 + 0) * 2 + 1] = r10;
        out[(b0 + 1) * 2 + 1] = r11;
    }
}

extern "C" void kernel_launch(void* const* d_in, const int* in_sizes, int n_in,
                              void* d_out, int out_size, void* d_ws, size_t ws_size,
                              hipStream_t stream) {
    const float* x    = (const float*)d_in[0];
    const float* w0   = (const float*)d_in[1];
    const float* ws   = (const float*)d_in[2];
    const int*   idx0 = (const int*)d_in[3];
    const int*   idxs = (const int*)d_in[4];
    float*       out  = (float*)d_out;
    float4*      cs   = (float4*)d_ws;   // LTOT*KN float4 = 384 KB of scratch

    coeff_kernel<<<(LTOT * KN + NTHREADS - 1) / NTHREADS, NTHREADS, 0, stream>>>(w0, ws, cs);
    fused_kernel<<<BATCH / 2, NTHREADS, 0, stream>>>(x, idx0, idxs, cs, out);
}

// Round 2
// 61.736 us; speedup vs baseline: 1.7549x; 1.7549x over previous
//
#include <hip/hip_runtime.h>
#include <hip/hip_fp16.h>

#define KN   4096
#define LTOT 6
#define BATCH 8192
#define ROWS 8
#define NT   1024
#define NBLK (BATCH / ROWS)

union F4H { float4 f; __half2 h[4]; };

// Precompute per-neuron logic coefficients as broadcast half2 pairs:
// per neuron 16 B = {c1,c1, ca,ca, cb,cb, cab,cab} in fp16.
__global__ __launch_bounds__(256) void coeff_kernel(const float* __restrict__ w0,
                                                    const float* __restrict__ ws,
                                                    float4* __restrict__ cs) {
    const float TAB[16][4] = {
        {0.f, 0.f, 0.f, 0.f}, {0.f, 0.f, 0.f, 1.f}, {0.f, 1.f, 0.f,-1.f}, {0.f, 1.f, 0.f, 0.f},
        {0.f, 0.f, 1.f,-1.f}, {0.f, 0.f, 1.f, 0.f}, {0.f, 1.f, 1.f,-2.f}, {0.f, 1.f, 1.f,-1.f},
        {1.f,-1.f,-1.f, 1.f}, {1.f,-1.f,-1.f, 2.f}, {1.f, 0.f,-1.f, 0.f}, {1.f, 0.f,-1.f, 1.f},
        {1.f,-1.f, 0.f, 0.f}, {1.f,-1.f, 0.f, 1.f}, {1.f, 0.f, 0.f,-1.f}, {1.f, 0.f, 0.f, 0.f}
    };
    int gid = blockIdx.x * 256 + threadIdx.x;
    if (gid >= LTOT * KN) return;
    int l = gid >> 12;
    int k = gid & (KN - 1);
    const float* w = (l == 0) ? (w0 + k * 16) : (ws + ((size_t)((l - 1) * KN + k) << 4));
    float wv[16];
    float m = -1e30f;
#pragma unroll
    for (int j = 0; j < 16; ++j) { wv[j] = w[j]; m = fmaxf(m, wv[j]); }
    float s = 0.f;
#pragma unroll
    for (int j = 0; j < 16; ++j) { wv[j] = __expf(wv[j] - m); s += wv[j]; }
    float inv = 1.0f / s;
    float c0 = 0.f, c1 = 0.f, c2 = 0.f, c3 = 0.f;
#pragma unroll
    for (int j = 0; j < 16; ++j) {
        c0 += wv[j] * TAB[j][0];
        c1 += wv[j] * TAB[j][1];
        c2 += wv[j] * TAB[j][2];
        c3 += wv[j] * TAB[j][3];
    }
    F4H u;
    u.h[0] = __float2half2_rn(c0 * inv);
    u.h[1] = __float2half2_rn(c1 * inv);
    u.h[2] = __float2half2_rn(c2 * inv);
    u.h[3] = __float2half2_rn(c3 * inv);
    cs[gid] = u.f;
}

// One block = 8 batch rows, packed per-neuron as 4x half2 (16 B) in LDS.
__global__ __launch_bounds__(NT, 4) void fused_kernel(const float* __restrict__ x,
                                                      const int* __restrict__ idx0,
                                                      const int* __restrict__ idxs,
                                                      const float4* __restrict__ cs,
                                                      float* __restrict__ out) {
    __shared__ float4 hbuf[2][KN];        // 128 KB
    __shared__ float red[16][16];         // 1 KB

    const int t  = threadIdx.x;
    const int b0 = blockIdx.x * ROWS;

    // Binarize 8 rows x 2 features; pack rows (2j, 2j+1) into half2 lanes.
    __half2 hin[2][4];
#pragma unroll
    for (int j = 0; j < 4; ++j) {
        float f0a = x[(size_t)(b0 + 2 * j)     * 2 + 0] > 0.f ? 1.f : 0.f;
        float f0b = x[(size_t)(b0 + 2 * j + 1) * 2 + 0] > 0.f ? 1.f : 0.f;
        float f1a = x[(size_t)(b0 + 2 * j)     * 2 + 1] > 0.f ? 1.f : 0.f;
        float f1b = x[(size_t)(b0 + 2 * j + 1) * 2 + 1] > 0.f ? 1.f : 0.f;
        hin[0][j] = __floats2half2_rn(f0a, f0b);
        hin[1][j] = __floats2half2_rn(f1a, f1b);
    }

    // Layer 0: 2 -> K
#pragma unroll
    for (int k = t; k < KN; k += NT) {
        int ia = idx0[k];
        int ib = idx0[KN + k];
        F4H c; c.f = cs[k];
        F4H o;
#pragma unroll
        for (int j = 0; j < 4; ++j) {
            __half2 a = ia ? hin[1][j] : hin[0][j];
            __half2 b = ib ? hin[1][j] : hin[0][j];
            o.h[j] = __hfma2(__hfma2(c.h[3], b, c.h[1]), a, __hfma2(c.h[2], b, c.h[0]));
        }
        hbuf[0][k] = o.f;
    }
    __syncthreads();

    // Layers 1..5: K -> K, ping-pong LDS buffers.
    int cur = 0;
    for (int l = 1; l < LTOT; ++l) {
        const int*    __restrict__ ixa = idxs + (size_t)(l - 1) * 2 * KN;
        const int*    __restrict__ ixb = ixa + KN;
        const float4* __restrict__ cl  = cs + (size_t)l * KN;
        const float4* hs = hbuf[cur];
        float4*       hd = hbuf[cur ^ 1];
#pragma unroll
        for (int k = t; k < KN; k += NT) {
            int ia = ixa[k];
            int ib = ixb[k];
            F4H c; c.f = cl[k];
            F4H a; a.f = hs[ia];
            F4H b; b.f = hs[ib];
            F4H o;
#pragma unroll
            for (int j = 0; j < 4; ++j)
                o.h[j] = __hfma2(__hfma2(c.h[3], b.h[j], c.h[1]), a.h[j],
                                 __hfma2(c.h[2], b.h[j], c.h[0]));
            hd[k] = o.f;
        }
        __syncthreads();
        cur ^= 1;
    }

    // GroupSum epilogue: class 0 = k in [0,2048), class 1 = k in [2048,4096).
    const float4* hf = hbuf[cur];
    float acc[16];   // [class*8 + row]
#pragma unroll
    for (int j = 0; j < 16; ++j) acc[j] = 0.f;
#pragma unroll
    for (int it = 0; it < 2; ++it) {
        int k = t + it * NT;             // [0, 2048)
        F4H v0; v0.f = hf[k];
        F4H v1; v1.f = hf[k + 2048];
#pragma unroll
        for (int j = 0; j < 4; ++j) {
            float2 f0 = __half22float2(v0.h[j]);
            float2 f1 = __half22float2(v1.h[j]);
            acc[2 * j]         += f0.x;
            acc[2 * j + 1]     += f0.y;
            acc[8 + 2 * j]     += f1.x;
            acc[8 + 2 * j + 1] += f1.y;
        }
    }
#pragma unroll
    for (int j = 0; j < 16; ++j)
#pragma unroll
        for (int off = 32; off > 0; off >>= 1)
            acc[j] += __shfl_down(acc[j], off);
    int wave = t >> 6, lane = t & 63;
    if (lane == 0) {
#pragma unroll
        for (int j = 0; j < 16; ++j) red[wave][j] = acc[j];
    }
    __syncthreads();
    if (t < 16) {
        float s = 0.f;
#pragma unroll
        for (int w = 0; w < 16; ++w) s += red[w][t];
        int cls = t >> 3, row = t & 7;
        out[(size_t)(b0 + row) * 2 + cls] = s;
    }
}

extern "C" void kernel_launch(void* const* d_in, const int* in_sizes, int n_in,
                              void* d_out, int out_size, void* d_ws, size_t ws_size,
                              hipStream_t stream) {
    const float* x    = (const float*)d_in[0];
    const float* w0   = (const float*)d_in[1];
    const float* ws   = (const float*)d_in[2];
    const int*   idx0 = (const int*)d_in[3];
    const int*   idxs = (const int*)d_in[4];
    float*       out  = (float*)d_out;
    float4*      cs   = (float4*)d_ws;   // LTOT*KN*16 B = 384 KB scratch

    coeff_kernel<<<(LTOT * KN + 255) / 256, 256, 0, stream>>>(w0, ws, cs);
    fused_kernel<<<NBLK, NT, 0, stream>>>(x, idx0, idxs, cs, out);
}

// Round 3
// 59.610 us; speedup vs baseline: 1.8175x; 1.0357x over previous
//
#include <hip/hip_runtime.h>
#include <hip/hip_fp16.h>

#define KN    4096
#define LTOT  6
#define BATCH 8192
#define ROWS  8
#define NT    1024
#define NITER (KN / NT)          // 4
#define NBLK  (BATCH / ROWS)     // 1024

union F4H { float4 f; __half2 h[4]; };

// Precompute per-neuron logic coefficients as broadcast half2 pairs:
// per neuron 16 B = {c1,c1, ca,ca, cb,cb, cab,cab} in fp16.
__global__ __launch_bounds__(256) void coeff_kernel(const float* __restrict__ w0,
                                                    const float* __restrict__ ws,
                                                    float4* __restrict__ cs) {
    const float TAB[16][4] = {
        {0.f, 0.f, 0.f, 0.f}, {0.f, 0.f, 0.f, 1.f}, {0.f, 1.f, 0.f,-1.f}, {0.f, 1.f, 0.f, 0.f},
        {0.f, 0.f, 1.f,-1.f}, {0.f, 0.f, 1.f, 0.f}, {0.f, 1.f, 1.f,-2.f}, {0.f, 1.f, 1.f,-1.f},
        {1.f,-1.f,-1.f, 1.f}, {1.f,-1.f,-1.f, 2.f}, {1.f, 0.f,-1.f, 0.f}, {1.f, 0.f,-1.f, 1.f},
        {1.f,-1.f, 0.f, 0.f}, {1.f,-1.f, 0.f, 1.f}, {1.f, 0.f, 0.f,-1.f}, {1.f, 0.f, 0.f, 0.f}
    };
    int gid = blockIdx.x * 256 + threadIdx.x;
    if (gid >= LTOT * KN) return;
    int l = gid >> 12;
    int k = gid & (KN - 1);
    const float* w = (l == 0) ? (w0 + k * 16) : (ws + ((size_t)((l - 1) * KN + k) << 4));
    float wv[16];
    float m = -1e30f;
#pragma unroll
    for (int j = 0; j < 16; ++j) { wv[j] = w[j]; m = fmaxf(m, wv[j]); }
    float s = 0.f;
#pragma unroll
    for (int j = 0; j < 16; ++j) { wv[j] = __expf(wv[j] - m); s += wv[j]; }
    float inv = 1.0f / s;
    float c0 = 0.f, c1 = 0.f, c2 = 0.f, c3 = 0.f;
#pragma unroll
    for (int j = 0; j < 16; ++j) {
        c0 += wv[j] * TAB[j][0];
        c1 += wv[j] * TAB[j][1];
        c2 += wv[j] * TAB[j][2];
        c3 += wv[j] * TAB[j][3];
    }
    F4H u;
    u.h[0] = __float2half2_rn(c0 * inv);
    u.h[1] = __float2half2_rn(c1 * inv);
    u.h[2] = __float2half2_rn(c2 * inv);
    u.h[3] = __float2half2_rn(c3 * inv);
    cs[gid] = u.f;
}

// One block = 8 batch rows, packed per-neuron as 4x half2 (16 B) in LDS.
// 2-deep register pipeline on idx/coeff: layer l+1's global loads are issued
// while layer l computes, so the pre-barrier vmcnt(0) drain is free.
__global__ __launch_bounds__(NT) void fused_kernel(const float* __restrict__ x,
                                                   const int* __restrict__ idx0,
                                                   const int* __restrict__ idxs,
                                                   const float4* __restrict__ cs,
                                                   float* __restrict__ out) {
    __shared__ float4 hbuf[2][KN];        // 128 KB
    __shared__ float red[16][16];         // 1 KB

    const int t  = threadIdx.x;
    const int b0 = blockIdx.x * ROWS;

    // Binarize 8 rows x 2 features; pack rows (2j, 2j+1) into half2 lanes.
    __half2 hin[2][4];
#pragma unroll
    for (int j = 0; j < 4; ++j) {
        float f0a = x[(size_t)(b0 + 2 * j)     * 2 + 0] > 0.f ? 1.f : 0.f;
        float f0b = x[(size_t)(b0 + 2 * j + 1) * 2 + 0] > 0.f ? 1.f : 0.f;
        float f1a = x[(size_t)(b0 + 2 * j)     * 2 + 1] > 0.f ? 1.f : 0.f;
        float f1b = x[(size_t)(b0 + 2 * j + 1) * 2 + 1] > 0.f ? 1.f : 0.f;
        hin[0][j] = __floats2half2_rn(f0a, f0b);
        hin[1][j] = __floats2half2_rn(f1a, f1b);
    }

    // ---- Layer 0 operand loads ----
    int ia0[NITER], ib0[NITER];
    float4 c0r[NITER];
#pragma unroll
    for (int i = 0; i < NITER; ++i) {
        int k = t + i * NT;
        ia0[i] = idx0[k];
        ib0[i] = idx0[KN + k];
        c0r[i] = cs[k];
    }

    // ---- Prefetch layer 1 idx/coeff into register set 1 ----
    int    pia[2][NITER], pib[2][NITER];
    float4 pc[2][NITER];
#pragma unroll
    for (int i = 0; i < NITER; ++i) {
        int k = t + i * NT;
        pia[1][i] = idxs[k];
        pib[1][i] = idxs[KN + k];
        pc[1][i]  = cs[KN + k];
    }

    // ---- Compute layer 0: 2 -> K ----
#pragma unroll
    for (int i = 0; i < NITER; ++i) {
        int k = t + i * NT;
        F4H c; c.f = c0r[i];
        F4H o;
#pragma unroll
        for (int j = 0; j < 4; ++j) {
            __half2 a = ia0[i] ? hin[1][j] : hin[0][j];
            __half2 b = ib0[i] ? hin[1][j] : hin[0][j];
            o.h[j] = __hfma2(__hfma2(c.h[3], b, c.h[1]), a, __hfma2(c.h[2], b, c.h[0]));
        }
        hbuf[0][k] = o.f;
    }
    __syncthreads();

    // ---- Layers 1..5: K -> K, ping-pong LDS, pipelined operand loads ----
    int cur = 0;
#pragma unroll
    for (int l = 1; l < LTOT; ++l) {
        const int s = l & 1;
        if (l + 1 < LTOT) {
            const int ns = (l + 1) & 1;
            const int* __restrict__ nxa = idxs + (size_t)l * 2 * KN;
            const float4* __restrict__ ncl = cs + (size_t)(l + 1) * KN;
#pragma unroll
            for (int i = 0; i < NITER; ++i) {
                int k = t + i * NT;
                pia[ns][i] = nxa[k];
                pib[ns][i] = nxa[KN + k];
                pc[ns][i]  = ncl[k];
            }
        }
        const float4* hs = hbuf[cur];
        float4*       hd = hbuf[cur ^ 1];
#pragma unroll
        for (int i = 0; i < NITER; ++i) {
            int k = t + i * NT;
            F4H c; c.f = pc[s][i];
            F4H a; a.f = hs[pia[s][i]];
            F4H b; b.f = hs[pib[s][i]];
            F4H o;
#pragma unroll
            for (int j = 0; j < 4; ++j)
                o.h[j] = __hfma2(__hfma2(c.h[3], b.h[j], c.h[1]), a.h[j],
                                 __hfma2(c.h[2], b.h[j], c.h[0]));
            hd[k] = o.f;
        }
        __syncthreads();
        cur ^= 1;
    }

    // ---- GroupSum epilogue: class 0 = [0,2048), class 1 = [2048,4096) ----
    const float4* hf = hbuf[cur];
    float acc[16];   // [class*8 + row]
#pragma unroll
    for (int j = 0; j < 16; ++j) acc[j] = 0.f;
#pragma unroll
    for (int it = 0; it < 2; ++it) {
        int k = t + it * NT;             // [0, 2048)
        F4H v0; v0.f = hf[k];
        F4H v1; v1.f = hf[k + 2048];
#pragma unroll
        for (int j = 0; j < 4; ++j) {
            float2 f0 = __half22float2(v0.h[j]);
            float2 f1 = __half22float2(v1.h[j]);
            acc[2 * j]         += f0.x;
            acc[2 * j + 1]     += f0.y;
            acc[8 + 2 * j]     += f1.x;
            acc[8 + 2 * j + 1] += f1.y;
        }
    }
#pragma unroll
    for (int j = 0; j < 16; ++j)
#pragma unroll
        for (int off = 32; off > 0; off >>= 1)
            acc[j] += __shfl_down(acc[j], off);
    int wave = t >> 6, lane = t & 63;
    if (lane == 0) {
#pragma unroll
        for (int j = 0; j < 16; ++j) red[wave][j] = acc[j];
    }
    __syncthreads();
    if (t < 16) {
        float s = 0.f;
#pragma unroll
        for (int w = 0; w < 16; ++w) s += red[w][t];
        int cls = t >> 3, row = t & 7;
        out[(size_t)(b0 + row) * 2 + cls] = s;
    }
}

extern "C" void kernel_launch(void* const* d_in, const int* in_sizes, int n_in,
                              void* d_out, int out_size, void* d_ws, size_t ws_size,
                              hipStream_t stream) {
    const float* x    = (const float*)d_in[0];
    const float* w0   = (const float*)d_in[1];
    const float* ws   = (const float*)d_in[2];
    const int*   idx0 = (const int*)d_in[3];
    const int*   idxs = (const int*)d_in[4];
    float*       out  = (float*)d_out;
    float4*      cs   = (float4*)d_ws;   // LTOT*KN*16 B = 384 KB scratch

    coeff_kernel<<<(LTOT * KN + 255) / 256, 256, 0, stream>>>(w0, ws, cs);
    fused_kernel<<<NBLK, NT, 0, stream>>>(x, idx0, idxs, cs, out);
}

// Round 4
// 56.106 us; speedup vs baseline: 1.9310x; 1.0624x over previous
//
#include <hip/hip_runtime.h>
#include <hip/hip_fp16.h>

#define KN    4096
#define LTOT  6
#define BATCH 8192
#define ROWS  4
#define NT    512
#define NITER (KN / NT)          // 8
#define NBLK  (BATCH / ROWS)     // 2048
#define NWAVE (NT / 64)          // 8

union F2H { float2 f; __half2 h[2]; };

// Pack per-neuron operands:
//   pidx[l*KN+k]  = ia | (ib << 16)
//   pcoef[l*KN+k] = {c1,ca,cb,cab} as 4x fp16 (8 B)
__global__ __launch_bounds__(256) void pack_kernel(const float* __restrict__ w0,
                                                   const float* __restrict__ ws,
                                                   const int* __restrict__ idx0,
                                                   const int* __restrict__ idxs,
                                                   unsigned* __restrict__ pidx,
                                                   float2* __restrict__ pcoef) {
    const float TAB[16][4] = {
        {0.f, 0.f, 0.f, 0.f}, {0.f, 0.f, 0.f, 1.f}, {0.f, 1.f, 0.f,-1.f}, {0.f, 1.f, 0.f, 0.f},
        {0.f, 0.f, 1.f,-1.f}, {0.f, 0.f, 1.f, 0.f}, {0.f, 1.f, 1.f,-2.f}, {0.f, 1.f, 1.f,-1.f},
        {1.f,-1.f,-1.f, 1.f}, {1.f,-1.f,-1.f, 2.f}, {1.f, 0.f,-1.f, 0.f}, {1.f, 0.f,-1.f, 1.f},
        {1.f,-1.f, 0.f, 0.f}, {1.f,-1.f, 0.f, 1.f}, {1.f, 0.f, 0.f,-1.f}, {1.f, 0.f, 0.f, 0.f}
    };
    int gid = blockIdx.x * 256 + threadIdx.x;
    if (gid >= LTOT * KN) return;
    int l = gid >> 12;
    int k = gid & (KN - 1);
    const float* w = (l == 0) ? (w0 + k * 16) : (ws + ((size_t)((l - 1) * KN + k) << 4));
    float wv[16];
    float m = -1e30f;
#pragma unroll
    for (int j = 0; j < 16; ++j) { wv[j] = w[j]; m = fmaxf(m, wv[j]); }
    float s = 0.f;
#pragma unroll
    for (int j = 0; j < 16; ++j) { wv[j] = __expf(wv[j] - m); s += wv[j]; }
    float inv = 1.0f / s;
    float c0 = 0.f, c1 = 0.f, c2 = 0.f, c3 = 0.f;
#pragma unroll
    for (int j = 0; j < 16; ++j) {
        c0 += wv[j] * TAB[j][0];
        c1 += wv[j] * TAB[j][1];
        c2 += wv[j] * TAB[j][2];
        c3 += wv[j] * TAB[j][3];
    }
    F2H u;
    u.h[0] = __floats2half2_rn(c0 * inv, c1 * inv);   // (c1, ca)
    u.h[1] = __floats2half2_rn(c2 * inv, c3 * inv);   // (cb, cab)
    pcoef[gid] = u.f;

    int ia, ib;
    if (l == 0) { ia = idx0[k];                          ib = idx0[KN + k]; }
    else        { ia = idxs[(size_t)(l - 1) * 2 * KN + k]; ib = idxs[(size_t)(l - 1) * 2 * KN + KN + k]; }
    pidx[gid] = (unsigned)ia | ((unsigned)ib << 16);
}

// One block = 4 batch rows, packed per-neuron as 2x half2 (8 B) in LDS.
// 64.5 KB LDS -> 2 resident blocks/CU for barrier overlap.
__global__ __launch_bounds__(NT) void fused_kernel(const float* __restrict__ x,
                                                   const unsigned* __restrict__ pidx,
                                                   const float2* __restrict__ pcoef,
                                                   float* __restrict__ out) {
    __shared__ float2 hbuf[2][KN];       // 64 KB
    __shared__ float red[NWAVE][8];

    const int t  = threadIdx.x;
    const int b0 = blockIdx.x * ROWS;

    // Binarize 4 rows x 2 features; rows (2j,2j+1) share a half2.
    __half2 hin[2][2];
#pragma unroll
    for (int j = 0; j < 2; ++j) {
        float f0a = x[(size_t)(b0 + 2 * j)     * 2 + 0] > 0.f ? 1.f : 0.f;
        float f0b = x[(size_t)(b0 + 2 * j + 1) * 2 + 0] > 0.f ? 1.f : 0.f;
        float f1a = x[(size_t)(b0 + 2 * j)     * 2 + 1] > 0.f ? 1.f : 0.f;
        float f1b = x[(size_t)(b0 + 2 * j + 1) * 2 + 1] > 0.f ? 1.f : 0.f;
        hin[0][j] = __floats2half2_rn(f0a, f0b);
        hin[1][j] = __floats2half2_rn(f1a, f1b);
    }

    // ---- Layer 0: 2 -> K ----
    {
        unsigned p[NITER];
        F2H      c[NITER];
#pragma unroll
        for (int i = 0; i < NITER; ++i) {
            int k = t + i * NT;
            p[i]   = pidx[k];
            c[i].f = pcoef[k];
        }
#pragma unroll
        for (int i = 0; i < NITER; ++i) {
            int k = t + i * NT;
            __half2 c1h  = __half2half2(__low2half(c[i].h[0]));
            __half2 cah  = __half2half2(__high2half(c[i].h[0]));
            __half2 cbh  = __half2half2(__low2half(c[i].h[1]));
            __half2 cabh = __half2half2(__high2half(c[i].h[1]));
            int ia = p[i] & 0xffff, ib = p[i] >> 16;
            F2H o;
#pragma unroll
            for (int j = 0; j < 2; ++j) {
                __half2 a = ia ? hin[1][j] : hin[0][j];
                __half2 b = ib ? hin[1][j] : hin[0][j];
                o.h[j] = __hfma2(__hfma2(cabh, b, cah), a, __hfma2(cbh, b, c1h));
            }
            hbuf[0][k] = o.f;
        }
    }
    __syncthreads();

    // ---- Layers 1..5: K -> K, ping-pong LDS ----
    int cur = 0;
#pragma unroll
    for (int l = 1; l < LTOT; ++l) {
        const unsigned* __restrict__ pi = pidx  + (size_t)l * KN;
        const float2*   __restrict__ pc = pcoef + (size_t)l * KN;
        unsigned p[NITER];
        F2H      c[NITER];
#pragma unroll
        for (int i = 0; i < NITER; ++i) {
            int k = t + i * NT;
            p[i]   = pi[k];
            c[i].f = pc[k];
        }
        const float2* hs = hbuf[cur];
        float2*       hd = hbuf[cur ^ 1];
#pragma unroll
        for (int i = 0; i < NITER; ++i) {
            int k = t + i * NT;
            F2H a; a.f = hs[p[i] & 0xffff];
            F2H b; b.f = hs[p[i] >> 16];
            __half2 c1h  = __half2half2(__low2half(c[i].h[0]));
            __half2 cah  = __half2half2(__high2half(c[i].h[0]));
            __half2 cbh  = __half2half2(__low2half(c[i].h[1]));
            __half2 cabh = __half2half2(__high2half(c[i].h[1]));
            F2H o;
#pragma unroll
            for (int j = 0; j < 2; ++j)
                o.h[j] = __hfma2(__hfma2(cabh, b.h[j], cah), a.h[j],
                                 __hfma2(cbh, b.h[j], c1h));
            hd[k] = o.f;
        }
        __syncthreads();
        cur ^= 1;
    }

    // ---- GroupSum: class 0 = [0,2048), class 1 = [2048,4096) ----
    const float2* hf = hbuf[cur];
    float acc[8];   // [class*4 + row]
#pragma unroll
    for (int j = 0; j < 8; ++j) acc[j] = 0.f;
#pragma unroll
    for (int it = 0; it < 4; ++it) {
        int k = t + it * NT;             // [0, 2048)
        F2H v0; v0.f = hf[k];
        F2H v1; v1.f = hf[k + 2048];
#pragma unroll
        for (int j = 0; j < 2; ++j) {
            float2 f0 = __half22float2(v0.h[j]);
            float2 f1 = __half22float2(v1.h[j]);
            acc[2 * j]         += f0.x;
            acc[2 * j + 1]     += f0.y;
            acc[4 + 2 * j]     += f1.x;
            acc[4 + 2 * j + 1] += f1.y;
        }
    }
#pragma unroll
    for (int j = 0; j < 8; ++j)
#pragma unroll
        for (int off = 32; off > 0; off >>= 1)
            acc[j] += __shfl_down(acc[j], off);
    int wave = t >> 6, lane = t & 63;
    if (lane == 0) {
#pragma unroll
        for (int j = 0; j < 8; ++j) red[wave][j] = acc[j];
    }
    __syncthreads();
    if (t < 8) {
        float s = 0.f;
#pragma unroll
        for (int w = 0; w < NWAVE; ++w) s += red[w][t];
        int cls = t >> 2, row = t & 3;
        out[(size_t)(b0 + row) * 2 + cls] = s;
    }
}

extern "C" void kernel_launch(void* const* d_in, const int* in_sizes, int n_in,
                              void* d_out, int out_size, void* d_ws, size_t ws_size,
                              hipStream_t stream) {
    const float* x    = (const float*)d_in[0];
    const float* w0   = (const float*)d_in[1];
    const float* ws   = (const float*)d_in[2];
    const int*   idx0 = (const int*)d_in[3];
    const int*   idxs = (const int*)d_in[4];
    float*       out  = (float*)d_out;

    float2*   pcoef = (float2*)d_ws;                   // LTOT*KN*8 B  = 192 KB
    unsigned* pidx  = (unsigned*)(pcoef + LTOT * KN);  // LTOT*KN*4 B  =  96 KB

    pack_kernel<<<(LTOT * KN + 255) / 256, 256, 0, stream>>>(w0, ws, idx0, idxs, pidx, pcoef);
    fused_kernel<<<NBLK, NT, 0, stream>>>(x, pidx, pcoef, out);
}

// Round 5
// 55.741 us; speedup vs baseline: 1.9437x; 1.0065x over previous
//
#include <hip/hip_runtime.h>
#include <hip/hip_fp16.h>

#define KN    4096
#define LTOT  6
#define BATCH 8192
#define ROWS  4
#define NT    512
#define NITER (KN / NT)          // 8
#define NBLK  (BATCH / ROWS)     // 2048
#define NWAVE (NT / 64)          // 8

union F2H { float2 f; __half2 h[2]; };

// Pack per-neuron operands:
//   pidx[l*KN+k]  = (ia*8) | ((ib*8) << 16)   -- pre-scaled LDS byte offsets
//   pcoef[l*KN+k] = {(c1,ca),(cb,cab)} as 4x fp16 (8 B)
__global__ __launch_bounds__(256) void pack_kernel(const float* __restrict__ w0,
                                                   const float* __restrict__ ws,
                                                   const int* __restrict__ idx0,
                                                   const int* __restrict__ idxs,
                                                   unsigned* __restrict__ pidx,
                                                   float2* __restrict__ pcoef) {
    const float TAB[16][4] = {
        {0.f, 0.f, 0.f, 0.f}, {0.f, 0.f, 0.f, 1.f}, {0.f, 1.f, 0.f,-1.f}, {0.f, 1.f, 0.f, 0.f},
        {0.f, 0.f, 1.f,-1.f}, {0.f, 0.f, 1.f, 0.f}, {0.f, 1.f, 1.f,-2.f}, {0.f, 1.f, 1.f,-1.f},
        {1.f,-1.f,-1.f, 1.f}, {1.f,-1.f,-1.f, 2.f}, {1.f, 0.f,-1.f, 0.f}, {1.f, 0.f,-1.f, 1.f},
        {1.f,-1.f, 0.f, 0.f}, {1.f,-1.f, 0.f, 1.f}, {1.f, 0.f, 0.f,-1.f}, {1.f, 0.f, 0.f, 0.f}
    };
    int gid = blockIdx.x * 256 + threadIdx.x;
    if (gid >= LTOT * KN) return;
    int l = gid >> 12;
    int k = gid & (KN - 1);
    const float* w = (l == 0) ? (w0 + k * 16) : (ws + ((size_t)((l - 1) * KN + k) << 4));
    float wv[16];
    float m = -1e30f;
#pragma unroll
    for (int j = 0; j < 16; ++j) { wv[j] = w[j]; m = fmaxf(m, wv[j]); }
    float s = 0.f;
#pragma unroll
    for (int j = 0; j < 16; ++j) { wv[j] = __expf(wv[j] - m); s += wv[j]; }
    float inv = 1.0f / s;
    float c0 = 0.f, c1 = 0.f, c2 = 0.f, c3 = 0.f;
#pragma unroll
    for (int j = 0; j < 16; ++j) {
        c0 += wv[j] * TAB[j][0];
        c1 += wv[j] * TAB[j][1];
        c2 += wv[j] * TAB[j][2];
        c3 += wv[j] * TAB[j][3];
    }
    F2H u;
    u.h[0] = __floats2half2_rn(c0 * inv, c1 * inv);   // (c1, ca)
    u.h[1] = __floats2half2_rn(c2 * inv, c3 * inv);   // (cb, cab)
    pcoef[gid] = u.f;

    int ia, ib;
    if (l == 0) { ia = idx0[k];                            ib = idx0[KN + k]; }
    else        { ia = idxs[(size_t)(l - 1) * 2 * KN + k]; ib = idxs[(size_t)(l - 1) * 2 * KN + KN + k]; }
    pidx[gid] = ((unsigned)ia * 8u) | (((unsigned)ib * 8u) << 16);
}

// LDS-drain-only barrier: leaves prefetch vmcnt loads in flight.
#define LBAR() do {                                         \
    asm volatile("s_waitcnt lgkmcnt(0)" ::: "memory");      \
    __builtin_amdgcn_s_barrier();                           \
    asm volatile("" ::: "memory");                          \
} while (0)

#define PREFETCH(SET, LYR) do {                                   \
    const unsigned* __restrict__ pi_ = pidx  + (LYR) * KN;        \
    const float2*   __restrict__ pc_ = pcoef + (LYR) * KN;        \
    _Pragma("unroll")                                             \
    for (int i = 0; i < NITER; ++i) {                             \
        int k_ = t + i * NT;                                      \
        p##SET[i]   = pi_[k_];                                    \
        c##SET[i].f = pc_[k_];                                    \
    }                                                             \
    __builtin_amdgcn_sched_barrier(0);                            \
} while (0)

// Layer LYR (1..5): reads hbuf[(LYR+1)&1], writes hbuf[LYR&1].
#define COMPUTE(SET, LYR) do {                                            \
    const char* hsrc_ = (const char*)(&hbuf[((LYR) + 1) & 1][0]);         \
    float2*     hd_   = &hbuf[(LYR) & 1][0];                              \
    _Pragma("unroll")                                                     \
    for (int i = 0; i < NITER; ++i) {                                     \
        int k_ = t + i * NT;                                              \
        unsigned pv_ = p##SET[i];                                         \
        F2H a_; a_.f = *(const float2*)(hsrc_ + (pv_ & 0xffffu));         \
        F2H b_; b_.f = *(const float2*)(hsrc_ + (pv_ >> 16));             \
        __half2 c1h_  = __half2half2(__low2half(c##SET[i].h[0]));         \
        __half2 cah_  = __half2half2(__high2half(c##SET[i].h[0]));        \
        __half2 cbh_  = __half2half2(__low2half(c##SET[i].h[1]));         \
        __half2 cabh_ = __half2half2(__high2half(c##SET[i].h[1]));        \
        F2H o_;                                                           \
        _Pragma("unroll")                                                 \
        for (int j = 0; j < 2; ++j)                                       \
            o_.h[j] = __hfma2(__hfma2(cabh_, a_.h[j], cbh_), b_.h[j],     \
                              __hfma2(cah_, a_.h[j], c1h_));              \
        hd_[k_] = o_.f;                                                   \
    }                                                                     \
} while (0)

__global__ __launch_bounds__(NT, 4) void fused_kernel(const float* __restrict__ x,
                                                      const unsigned* __restrict__ pidx,
                                                      const float2* __restrict__ pcoef,
                                                      float* __restrict__ out) {
    __shared__ float2 hbuf[2][KN];       // 64 KB -> 2 blocks/CU
    __shared__ float red[NWAVE][8];

    const int t  = threadIdx.x;
    const int b0 = blockIdx.x * ROWS;

    // Binarize 4 rows x 2 features; rows (2j,2j+1) share a half2.
    __half2 hin[2][2];
#pragma unroll
    for (int j = 0; j < 2; ++j) {
        float f0a = x[(size_t)(b0 + 2 * j)     * 2 + 0] > 0.f ? 1.f : 0.f;
        float f0b = x[(size_t)(b0 + 2 * j + 1) * 2 + 0] > 0.f ? 1.f : 0.f;
        float f1a = x[(size_t)(b0 + 2 * j)     * 2 + 1] > 0.f ? 1.f : 0.f;
        float f1b = x[(size_t)(b0 + 2 * j + 1) * 2 + 1] > 0.f ? 1.f : 0.f;
        hin[0][j] = __floats2half2_rn(f0a, f0b);
        hin[1][j] = __floats2half2_rn(f1a, f1b);
    }

    // Operand register sets: O (layer 0), A/B alternate for layers 1..5.
    unsigned pO[NITER], pA[NITER], pB[NITER];
    F2H      cO[NITER], cA[NITER], cB[NITER];

    // Load layer-0 operands, then prefetch layer 1 before computing.
#pragma unroll
    for (int i = 0; i < NITER; ++i) {
        int k = t + i * NT;
        pO[i]   = pidx[k];
        cO[i].f = pcoef[k];
    }
    PREFETCH(A, 1);

    // ---- Layer 0: 2 -> K, writes hbuf[0] ----
#pragma unroll
    for (int i = 0; i < NITER; ++i) {
        int k = t + i * NT;
        __half2 c1h  = __half2half2(__low2half(cO[i].h[0]));
        __half2 cah  = __half2half2(__high2half(cO[i].h[0]));
        __half2 cbh  = __half2half2(__low2half(cO[i].h[1]));
        __half2 cabh = __half2half2(__high2half(cO[i].h[1]));
        F2H o;
#pragma unroll
        for (int j = 0; j < 2; ++j) {
            __half2 a = (pO[i] & 0xffffu) ? hin[1][j] : hin[0][j];
            __half2 b = (pO[i] >> 16)     ? hin[1][j] : hin[0][j];
            o.h[j] = __hfma2(__hfma2(cabh, a, cbh), b, __hfma2(cah, a, c1h));
        }
        hbuf[0][k] = o.f;
    }
    LBAR();

    // ---- Layers 1..5, software-pipelined operand loads ----
    PREFETCH(B, 2);  COMPUTE(A, 1);  LBAR();
    PREFETCH(A, 3);  COMPUTE(B, 2);  LBAR();
    PREFETCH(B, 4);  COMPUTE(A, 3);  LBAR();
    PREFETCH(A, 5);  COMPUTE(B, 4);  LBAR();
    COMPUTE(A, 5);   LBAR();

    // ---- GroupSum: final activations in hbuf[1] ----
    const float2* hf = &hbuf[1][0];
    float acc[8];   // [class*4 + row]
#pragma unroll
    for (int j = 0; j < 8; ++j) acc[j] = 0.f;
#pragma unroll
    for (int it = 0; it < 4; ++it) {
        int k = t + it * NT;             // [0, 2048)
        F2H v0; v0.f = hf[k];
        F2H v1; v1.f = hf[k + 2048];
#pragma unroll
        for (int j = 0; j < 2; ++j) {
            float2 f0 = __half22float2(v0.h[j]);
            float2 f1 = __half22float2(v1.h[j]);
            acc[2 * j]         += f0.x;
            acc[2 * j + 1]     += f0.y;
            acc[4 + 2 * j]     += f1.x;
            acc[4 + 2 * j + 1] += f1.y;
        }
    }
#pragma unroll
    for (int j = 0; j < 8; ++j)
#pragma unroll
        for (int off = 32; off > 0; off >>= 1)
            acc[j] += __shfl_down(acc[j], off);
    int wave = t >> 6, lane = t & 63;
    if (lane == 0) {
#pragma unroll
        for (int j = 0; j < 8; ++j) red[wave][j] = acc[j];
    }
    __syncthreads();
    if (t < 8) {
        float s = 0.f;
#pragma unroll
        for (int w = 0; w < NWAVE; ++w) s += red[w][t];
        int cls = t >> 2, row = t & 3;
        out[(size_t)(b0 + row) * 2 + cls] = s;
    }
}

extern "C" void kernel_launch(void* const* d_in, const int* in_sizes, int n_in,
                              void* d_out, int out_size, void* d_ws, size_t ws_size,
                              hipStream_t stream) {
    const float* x    = (const float*)d_in[0];
    const float* w0   = (const float*)d_in[1];
    const float* ws   = (const float*)d_in[2];
    const int*   idx0 = (const int*)d_in[3];
    const int*   idxs = (const int*)d_in[4];
    float*       out  = (float*)d_out;

    float2*   pcoef = (float2*)d_ws;                   // LTOT*KN*8 B  = 192 KB
    unsigned* pidx  = (unsigned*)(pcoef + LTOT * KN);  // LTOT*KN*4 B  =  96 KB

    pack_kernel<<<(LTOT * KN + 255) / 256, 256, 0, stream>>>(w0, ws, idx0, idxs, pidx, pcoef);
    fused_kernel<<<NBLK, NT, 0, stream>>>(x, pidx, pcoef, out);
}

// Round 6
// 50.525 us; speedup vs baseline: 2.1444x; 1.1033x over previous
//
#include <hip/hip_runtime.h>
#include <hip/hip_fp16.h>

#define KN    4096
#define LTOT  6
#define BATCH 8192
#define ROWS  4
#define NT    512
#define NITER (KN / NT)          // 8
#define NBLK  (BATCH / ROWS)     // 2048
#define NWAVE (NT / 64)          // 8

#if __has_builtin(__builtin_amdgcn_cvt_pk_u8_f32)
#define CVT_PK_U8(o, r, enc) __builtin_amdgcn_cvt_pk_u8_f32((o), (r), (enc))
#else
#define CVT_PK_U8(o, r, enc) ((enc) | ((unsigned)(int)(o) << (8 * (r))))
#endif

// Packed operand record, 12 B/neuron:
//   x = (ia*4) | ((ib*4) << 16)        -- pre-scaled LDS byte offsets (u32 slots)
//   y = half2(255*c1 + 0.5, ca)        -- quantization scale + rounding bias folded in
//   z = half2(cb, cab/255)
__global__ __launch_bounds__(256) void pack_kernel(const float* __restrict__ w0,
                                                   const float* __restrict__ ws,
                                                   const int* __restrict__ idx0,
                                                   const int* __restrict__ idxs,
                                                   uint3* __restrict__ pk) {
    const float TAB[16][4] = {
        {0.f, 0.f, 0.f, 0.f}, {0.f, 0.f, 0.f, 1.f}, {0.f, 1.f, 0.f,-1.f}, {0.f, 1.f, 0.f, 0.f},
        {0.f, 0.f, 1.f,-1.f}, {0.f, 0.f, 1.f, 0.f}, {0.f, 1.f, 1.f,-2.f}, {0.f, 1.f, 1.f,-1.f},
        {1.f,-1.f,-1.f, 1.f}, {1.f,-1.f,-1.f, 2.f}, {1.f, 0.f,-1.f, 0.f}, {1.f, 0.f,-1.f, 1.f},
        {1.f,-1.f, 0.f, 0.f}, {1.f,-1.f, 0.f, 1.f}, {1.f, 0.f, 0.f,-1.f}, {1.f, 0.f, 0.f, 0.f}
    };
    int gid = blockIdx.x * 256 + threadIdx.x;
    if (gid >= LTOT * KN) return;
    int l = gid >> 12;
    int k = gid & (KN - 1);
    const float* w = (l == 0) ? (w0 + k * 16) : (ws + ((size_t)((l - 1) * KN + k) << 4));
    float wv[16];
    float m = -1e30f;
#pragma unroll
    for (int j = 0; j < 16; ++j) { wv[j] = w[j]; m = fmaxf(m, wv[j]); }
    float s = 0.f;
#pragma unroll
    for (int j = 0; j < 16; ++j) { wv[j] = __expf(wv[j] - m); s += wv[j]; }
    float inv = 1.0f / s;
    float c0 = 0.f, c1 = 0.f, c2 = 0.f, c3 = 0.f;
#pragma unroll
    for (int j = 0; j < 16; ++j) {
        c0 += wv[j] * TAB[j][0];
        c1 += wv[j] * TAB[j][1];
        c2 += wv[j] * TAB[j][2];
        c3 += wv[j] * TAB[j][3];
    }
    c0 *= inv; c1 *= inv; c2 *= inv; c3 *= inv;

    __half2 y = __floats2half2_rn(255.0f * c0 + 0.5f, c1);
    __half2 z = __floats2half2_rn(c2, c3 * (1.0f / 255.0f));

    int ia, ib;
    if (l == 0) { ia = idx0[k];                            ib = idx0[KN + k]; }
    else        { ia = idxs[(size_t)(l - 1) * 2 * KN + k]; ib = idxs[(size_t)(l - 1) * 2 * KN + KN + k]; }

    uint3 e;
    e.x = ((unsigned)ia * 4u) | (((unsigned)ib * 4u) << 16);
    e.y = *(const unsigned*)&y;
    e.z = *(const unsigned*)&z;
    pk[gid] = e;
}

// One block = 4 batch rows packed as 4x u8 per neuron (one u32) in LDS.
// hbuf = 2 x 16 KB -> 4 blocks/CU, 32 waves/CU (launch_bounds forces <=64 VGPR).
__global__ __launch_bounds__(NT, 8) void fused_kernel(const float* __restrict__ x,
                                                      const uint3* __restrict__ pk,
                                                      float* __restrict__ out) {
    __shared__ unsigned hbuf[2][KN];     // 32 KB
    __shared__ float red[NWAVE][8];

    const int t  = threadIdx.x;
    const int b0 = blockIdx.x * ROWS;

    // Features as 0/255 floats per row.
    float f0[ROWS], f1[ROWS];
#pragma unroll
    for (int r = 0; r < ROWS; ++r) {
        f0[r] = x[(size_t)(b0 + r) * 2 + 0] > 0.f ? 255.f : 0.f;
        f1[r] = x[(size_t)(b0 + r) * 2 + 1] > 0.f ? 255.f : 0.f;
    }

    // ---- Layer 0: 2 -> K, writes hbuf[0] ----
#pragma unroll
    for (int i = 0; i < NITER; ++i) {
        int k = t + i * NT;
        uint3 e = pk[k];
        float2 cA = __half22float2(*(const __half2*)&e.y);   // (c1'', ca)
        float2 cB = __half22float2(*(const __half2*)&e.z);   // (cb, cab')
        unsigned enc = 0;
#pragma unroll
        for (int r = 0; r < ROWS; ++r) {
            float A = (e.x & 0xffffu) ? f1[r] : f0[r];
            float B = (e.x >> 16)     ? f1[r] : f0[r];
            float o = fmaf(fmaf(cB.y, B, cA.y), A, fmaf(cB.x, B, cA.x));
            enc = CVT_PK_U8(o, r, enc);
        }
        hbuf[0][k] = enc;
    }
    __syncthreads();

    // ---- Layers 1..4: K -> K, ping-pong ----
#pragma unroll
    for (int l = 1; l <= 4; ++l) {
        const uint3* __restrict__ pl = pk + (size_t)l * KN;
        const char* hs = (const char*)&hbuf[(l + 1) & 1][0];
        unsigned*   hd = &hbuf[l & 1][0];
#pragma unroll
        for (int i = 0; i < NITER; ++i) {
            int k = t + i * NT;
            uint3 e = pl[k];
            unsigned av = *(const unsigned*)(hs + (e.x & 0xffffu));
            unsigned bv = *(const unsigned*)(hs + (e.x >> 16));
            float2 cA = __half22float2(*(const __half2*)&e.y);
            float2 cB = __half22float2(*(const __half2*)&e.z);
            unsigned enc = 0;
#pragma unroll
            for (int r = 0; r < ROWS; ++r) {
                float A = (float)((av >> (8 * r)) & 0xffu);
                float B = (float)((bv >> (8 * r)) & 0xffu);
                float o = fmaf(fmaf(cB.y, B, cA.y), A, fmaf(cB.x, B, cA.x));
                enc = CVT_PK_U8(o, r, enc);
            }
            hd[k] = enc;
        }
        __syncthreads();
    }

    // ---- Layer 5 fused with GroupSum (reads hbuf[0], no quantize/write) ----
    float acc[8];    // [class*4 + row], values are 255*f + 0.5
#pragma unroll
    for (int j = 0; j < 8; ++j) acc[j] = 0.f;
    {
        const uint3* __restrict__ p5 = pk + (size_t)5 * KN;
        const char* hs = (const char*)&hbuf[0][0];
#pragma unroll
        for (int i = 0; i < NITER; ++i) {
            int k = t + i * NT;
            uint3 e = p5[k];
            unsigned av = *(const unsigned*)(hs + (e.x & 0xffffu));
            unsigned bv = *(const unsigned*)(hs + (e.x >> 16));
            float2 cA = __half22float2(*(const __half2*)&e.y);
            float2 cB = __half22float2(*(const __half2*)&e.z);
            const int cbase = (i >= 4) ? 4 : 0;   // class from k = t + i*512
#pragma unroll
            for (int r = 0; r < ROWS; ++r) {
                float A = (float)((av >> (8 * r)) & 0xffu);
                float B = (float)((bv >> (8 * r)) & 0xffu);
                acc[cbase + r] += fmaf(fmaf(cB.y, B, cA.y), A, fmaf(cB.x, B, cA.x));
            }
        }
    }
#pragma unroll
    for (int j = 0; j < 8; ++j)
#pragma unroll
        for (int off = 32; off > 0; off >>= 1)
            acc[j] += __shfl_down(acc[j], off);
    int wave = t >> 6, lane = t & 63;
    if (lane == 0) {
#pragma unroll
        for (int j = 0; j < 8; ++j) red[wave][j] = acc[j];
    }
    __syncthreads();
    if (t < 8) {
        float s = 0.f;
#pragma unroll
        for (int w = 0; w < NWAVE; ++w) s += red[w][t];
        // Each class-sum accumulated 2048 terms of (255*f + 0.5).
        s = (s - 1024.0f) * (1.0f / 255.0f);
        int cls = t >> 2, row = t & 3;
        out[(size_t)(b0 + row) * 2 + cls] = s;
    }
}

extern "C" void kernel_launch(void* const* d_in, const int* in_sizes, int n_in,
                              void* d_out, int out_size, void* d_ws, size_t ws_size,
                              hipStream_t stream) {
    const float* x    = (const float*)d_in[0];
    const float* w0   = (const float*)d_in[1];
    const float* ws   = (const float*)d_in[2];
    const int*   idx0 = (const int*)d_in[3];
    const int*   idxs = (const int*)d_in[4];
    float*       out  = (float*)d_out;
    uint3*       pk   = (uint3*)d_ws;    // LTOT*KN*12 B = 288 KB scratch

    pack_kernel<<<(LTOT * KN + 255) / 256, 256, 0, stream>>>(w0, ws, idx0, idxs, pk);
    fused_kernel<<<NBLK, NT, 0, stream>>>(x, pk, out);
}